// Round 6
// baseline (705.852 us; speedup 1.0000x reference)
//
#include <hip/hip_runtime.h>
#include <hip/hip_bf16.h>

typedef __attribute__((ext_vector_type(4))) float f32x4;
typedef __attribute__((ext_vector_type(8))) short bf16x8;

__device__ __forceinline__ short f2bf(float x){
    __hip_bfloat16 h = __float2bfloat16(x);
    return __builtin_bit_cast(short, h);
}
__device__ __forceinline__ float bf2f(short x){
    unsigned int u = ((unsigned int)(unsigned short)x) << 16;
    return __builtin_bit_cast(float, u);
}

// ---------------------------------------------------------------- prep: tiled bf16 weights
// W2Tt  [9216 chunks of 8]:  chunk=(s*12+t)*64+lane -> W2[k][n],  n=t*16+(lane&15), k=s*32+((lane>>4)&3)*8+j
// W1aT/W1bT [147456 each]:   chunk=(s*24+t)*64+lane -> W1[k(+384)][n], s<12, t<24
// W1cd  [768]: (s*4+quad)*16 + h*8 + j -> bf16 of W1[768+h][s*32+quad*8+j]  (h=0: dense col, h=1: sparse col)
__global__ void prep_kernel(const float* __restrict__ W1, const float* __restrict__ W2,
                            short* __restrict__ W2Tt, short* __restrict__ W1aT,
                            short* __restrict__ W1bT, short* __restrict__ W1cd){
    int i = blockIdx.x*256 + threadIdx.x;           // 369408 total = 1443*256 exactly
    if (i < 73728){
        int j = i & 7, c = i >> 3;
        int lane = c & 63, st = c >> 6;             // st < 144
        int s = st/12, t = st%12;
        int n = t*16 + (lane&15), k = s*32 + ((lane>>4)&3)*8 + j;
        W2Tt[i] = f2bf(W2[k*192 + n]);
    } else if (i < 368640){
        int i2 = i - 73728;                         // i2 < 294912
        int part = i2 / 147456;                     // 0 = A (query side), 1 = B (doc side)
        int o = i2 % 147456;
        int j = o & 7, c = o >> 3;
        int lane = c & 63, st = c >> 6;             // st < 288
        int s = st/24, t = st%24;                   // s < 12, t < 24
        int n = t*16 + (lane&15), k = s*32 + ((lane>>4)&3)*8 + j;
        short v = f2bf(W1[(part*384 + k)*384 + n]);
        if (part) W1bT[o] = v; else W1aT[o] = v;
    } else {
        int o3 = i - 368640;                        // o3 < 768
        int j = o3 & 7, h = (o3>>3)&1, quad = (o3>>4)&3, s = o3>>6;
        int k = s*32 + quad*8 + j;
        W1cd[o3] = f2bf(W1[(768+h)*384 + k]);
    }
}

// ---------------------------------------------------------------- ab: MFMA GEMM
// blocks 0..255: Bws(bf16)[r0..r0+15] = doc rows @ W1b;  blocks 256..257: Aq(f32) = query @ W1a + b1.
__global__ __launch_bounds__(256)
void ab_kernel(const float* __restrict__ doc, const float* __restrict__ query,
               const short* __restrict__ W1aT, const short* __restrict__ W1bT,
               const float* __restrict__ b1,
               short* __restrict__ Bws, float* __restrict__ Aq){
    const int b = blockIdx.x, tid = threadIdx.x;
    const int w = tid >> 6, lane = tid & 63;
    const int cl = lane & 15, quad = lane >> 4;
    const float* src; const short* wt; int r0; bool isA;
    if (b < 256){ r0 = b*16;       src = doc;   wt = W1bT; isA = false; }
    else        { r0 = (b-256)*16; src = query; wt = W1aT; isA = true;  }

    f32x4 acc[6];
    #pragma unroll
    for (int t=0;t<6;t++) acc[t] = (f32x4){0.f,0.f,0.f,0.f};

    #pragma unroll
    for (int s=0;s<12;s++){
        const float* ap = src + (r0+cl)*384 + s*32 + quad*8;
        const f32x4 a0 = *(const f32x4*)ap;
        const f32x4 a1 = *(const f32x4*)(ap+4);
        bf16x8 af;
        #pragma unroll
        for (int j=0;j<4;j++){ af[j] = f2bf(a0[j]); af[4+j] = f2bf(a1[j]); }
        #pragma unroll
        for (int tt=0;tt<6;tt++){
            const bf16x8 bf_ = *(const bf16x8*)(wt + ((s*24 + w*6 + tt)*64 + lane)*8);
            acc[tt] = __builtin_amdgcn_mfma_f32_16x16x32_bf16(af, bf_, acc[tt], 0, 0, 0);
        }
    }
    // D layout: col=lane&15, row=quad*4+r
    #pragma unroll
    for (int tt=0;tt<6;tt++){
        const int col = (w*6+tt)*16 + cl;
        if (isA){
            const float b1v = b1[col];
            #pragma unroll
            for (int r=0;r<4;r++)
                Aq[(r0 + quad*4 + r)*384 + col] = acc[tt][r] + b1v;
        } else {
            #pragma unroll
            for (int r=0;r<4;r++)
                Bws[(r0 + quad*4 + r)*384 + col] = f2bf(acc[tt][r]);
        }
    }
}

// ---------------------------------------------------------------- dense scores + sparse copy
__global__ void dense_sparse_kernel(const float* __restrict__ query, const float* __restrict__ doc,
                                    const float* __restrict__ sparse, float* __restrict__ out_dense,
                                    float* __restrict__ out_sparse){
    __shared__ float ldsq[32*388];
    __shared__ float ldsd[16*388];
    const int tid = threadIdx.x, d0 = blockIdx.x*16;
    #pragma unroll
    for (int i=0;i<12;i++){ int idx = tid + i*256; int row = idx/96, c4 = idx%96;
        *(f32x4*)(ldsq + row*388 + c4*4) = *(const f32x4*)(query + row*384 + c4*4); }
    #pragma unroll
    for (int i=0;i<6;i++){ int idx = tid + i*256; int row = idx/96, c4 = idx%96;
        *(f32x4*)(ldsd + row*388 + c4*4) = *(const f32x4*)(doc + (d0+row)*384 + c4*4); }
    __syncthreads();
    const int q = tid>>3, dg = tid&7;
    float acc0 = 0.0f, acc1 = 0.0f;
    #pragma unroll 4
    for (int k=0;k<384;k++){
        float qv = ldsq[q*388 + k];
        acc0 += qv*ldsd[dg*388 + k];
        acc1 += qv*ldsd[(dg+8)*388 + k];
    }
    out_dense[q*4096 + d0 + dg]     = acc0;
    out_dense[q*4096 + d0 + dg + 8] = acc1;
    if (tid < 128){
        int qq = tid>>2, c4 = tid&3;
        *(f32x4*)(out_sparse + qq*4096 + d0 + c4*4) = *(const f32x4*)(sparse + qq*4096 + d0 + c4*4);
    }
}

// ---------------------------------------------------------------- main fused MLP kernel
// 256 blocks x 512 thr. LDS 147,456 B -> 1 block/CU = 8 waves = 2 waves/EU.
// waves_per_eu(2,2) unlocks the 256-VGPR budget that occupancy already permits (kills spill).
__global__ __attribute__((amdgpu_flat_work_group_size(512,512), amdgpu_waves_per_eu(2,2)))
void main_kernel(const float* __restrict__ Aq, const short* __restrict__ Bws,
                 const short* __restrict__ W1cd,
                 const float* __restrict__ b2, const float* __restrict__ W3,
                 const float* __restrict__ b3, const float* __restrict__ sparse,
                 const short* __restrict__ W2Tt, const float* __restrict__ dense_in,
                 float* __restrict__ out_final){
    __shared__ short lw[73728];                      // 147,456 bytes
    const int tid = threadIdx.x;
    #pragma unroll
    for (int i=0;i<18;i++){                          // 9216 x 16B linear copy
        int idx = tid + i*512;
        *(bf16x8*)(lw + idx*8) = *(const bf16x8*)(W2Tt + idx*8);
    }
    __syncthreads();                                 // only barrier

    const int lane = tid & 63, w = tid >> 6;
    const int cl = lane & 15, quad = lane >> 4;
    float b2r[12], w3r[12];
    #pragma unroll
    for (int t=0;t<12;t++){ b2r[t] = b2[t*16 + cl]; w3r[t] = W3[t*16 + cl]; }
    const float b3v = b3[0];

    #pragma unroll 1
    for (int t4=0; t4<4; t4++){
        const int R0 = blockIdx.x*512 + t4*128 + w*16;   // 16 rows: 16 q's of one doc
        const int dcol = R0 >> 5;
        const int q0 = R0 & 31;
        const int q = q0 + cl;
        const float dsv = dense_in[q*4096 + dcol];
        const float ssv = sparse[q*4096 + dcol];

        f32x4 acc[12];
        #pragma unroll
        for (int t=0;t<12;t++) acc[t] = (f32x4){0.f,0.f,0.f,0.f};

        #pragma unroll
        for (int s=0;s<12;s++){
            const int k0 = s*32 + quad*8;
            // layer 1 for this kstep, directly in A-fragment layout (b1 pre-folded into Aq)
            const f32x4 a0   = *(const f32x4*)(Aq + q*384 + k0);
            const f32x4 a1   = *(const f32x4*)(Aq + q*384 + k0 + 4);
            const bf16x8 bw  = *(const bf16x8*)(Bws + dcol*384 + k0);
            const bf16x8 wcv = *(const bf16x8*)(W1cd + (s*4 + quad)*16);
            const bf16x8 wdv = *(const bf16x8*)(W1cd + (s*4 + quad)*16 + 8);
            bf16x8 fr;
            #pragma unroll
            for (int j=0;j<4;j++){
                float h = a0[j] + bf2f(bw[j]) + dsv*bf2f(wcv[j]) + ssv*bf2f(wdv[j]);
                fr[j] = f2bf(fmaxf(h, 0.0f));
            }
            #pragma unroll
            for (int j=0;j<4;j++){
                float h = a1[j] + bf2f(bw[4+j]) + dsv*bf2f(wcv[4+j]) + ssv*bf2f(wdv[4+j]);
                fr[4+j] = f2bf(fmaxf(h, 0.0f));
            }
            #pragma unroll
            for (int t=0;t<12;t++){
                const bf16x8 bfr = *(const bf16x8*)(lw + ((s*12 + t)*64 + lane)*8);
                acc[t] = __builtin_amdgcn_mfma_f32_16x16x32_bf16(fr, bfr, acc[t], 0, 0, 0);
            }
        }

        // layer 3 + sigmoid blend. D layout: col=lane&15 -> n, row=quad*4+r
        float p[4] = {0.f,0.f,0.f,0.f};
        #pragma unroll
        for (int t=0;t<12;t++){
            #pragma unroll
            for (int r=0;r<4;r++)
                p[r] += fmaxf(acc[t][r] + b2r[t], 0.0f) * w3r[t];
        }
        #pragma unroll
        for (int m=1; m<16; m<<=1){
            #pragma unroll
            for (int r=0;r<4;r++) p[r] += __shfl_xor(p[r], m);
        }
        if (cl == 0){
            #pragma unroll
            for (int r=0;r<4;r++){
                int qq = q0 + quad*4 + r;
                float logit = p[r] + b3v;
                float wgt = 1.0f/(1.0f + __expf(-logit));
                float dd = dense_in[qq*4096 + dcol];
                float ss = sparse[qq*4096 + dcol];
                out_final[qq*4096 + dcol] = wgt*dd + (1.0f - wgt)*ss;
            }
        }
    }
}

// ---------------------------------------------------------------- launch
extern "C" void kernel_launch(void* const* d_in, const int* in_sizes, int n_in,
                              void* d_out, int out_size, void* d_ws, size_t ws_size,
                              hipStream_t stream){
    const float* query  = (const float*)d_in[0];
    const float* doc    = (const float*)d_in[1];
    const float* sparse = (const float*)d_in[2];
    const float* W1     = (const float*)d_in[3];
    const float* b1     = (const float*)d_in[4];
    const float* W2     = (const float*)d_in[5];
    const float* b2     = (const float*)d_in[6];
    const float* W3     = (const float*)d_in[7];
    const float* b3     = (const float*)d_in[8];

    float* out_final  = (float*)d_out;                 // [32,4096]
    float* out_dense  = (float*)d_out + 131072;        // [32,4096]
    float* out_sparse = (float*)d_out + 262144;        // [32,4096]

    // workspace layout (16B-aligned), total 3,933,696 B
    short* Bws  = (short*)d_ws;                                   // 3,145,728 B  (bf16 [4096][384])
    float* Aq   = (float*)((char*)d_ws + 3145728);                //    49,152 B  (f32  [32][384])
    short* W2Tt = (short*)((char*)d_ws + 3194880);                //   147,456 B
    short* W1aT = (short*)((char*)d_ws + 3342336);                //   294,912 B
    short* W1bT = (short*)((char*)d_ws + 3637248);                //   294,912 B
    short* W1cd = (short*)((char*)d_ws + 3932160);                //     1,536 B

    hipLaunchKernelGGL(prep_kernel,         dim3(1443), dim3(256), 0, stream, W1, W2, W2Tt, W1aT, W1bT, W1cd);
    hipLaunchKernelGGL(ab_kernel,           dim3(258),  dim3(256), 0, stream, doc, query, W1aT, W1bT, b1, Bws, Aq);
    hipLaunchKernelGGL(dense_sparse_kernel, dim3(256),  dim3(256), 0, stream, query, doc, sparse, out_dense, out_sparse);
    hipLaunchKernelGGL(main_kernel,         dim3(256),  dim3(512), 0, stream,
                       Aq, Bws, W1cd, b2, W3, b3, sparse, W2Tt, out_dense, out_final);
}

// Round 7
// 337.954 us; speedup vs baseline: 2.0886x; 2.0886x over previous
//
#include <hip/hip_runtime.h>
#include <hip/hip_bf16.h>

typedef __attribute__((ext_vector_type(4))) float f32x4;
typedef __attribute__((ext_vector_type(8))) short bf16x8;

__device__ __forceinline__ short f2bf(float x){
    __hip_bfloat16 h = __float2bfloat16(x);
    return __builtin_bit_cast(short, h);
}
__device__ __forceinline__ float bf2f(short x){
    unsigned int u = ((unsigned int)(unsigned short)x) << 16;
    return __builtin_bit_cast(float, u);
}

// ---------------------------------------------------------------- prep: tiled bf16 weights
// W2Tt  [9216 chunks of 8]:  chunk=(s*12+t)*64+lane -> W2[k][n],  n=t*16+(lane&15), k=s*32+((lane>>4)&3)*8+j
// W1aT/W1bT [147456 each]:   chunk=(s*24+t)*64+lane -> W1[k(+384)][n], s<12, t<24
// W1cd  [768]: (s*4+quad)*16 + h*8 + j -> bf16 of W1[768+h][s*32+quad*8+j]
__global__ void prep_kernel(const float* __restrict__ W1, const float* __restrict__ W2,
                            short* __restrict__ W2Tt, short* __restrict__ W1aT,
                            short* __restrict__ W1bT, short* __restrict__ W1cd){
    int i = blockIdx.x*256 + threadIdx.x;           // 369408 total = 1443*256 exactly
    if (i < 73728){
        int j = i & 7, c = i >> 3;
        int lane = c & 63, st = c >> 6;             // st < 144
        int s = st/12, t = st%12;
        int n = t*16 + (lane&15), k = s*32 + ((lane>>4)&3)*8 + j;
        W2Tt[i] = f2bf(W2[k*192 + n]);
    } else if (i < 368640){
        int i2 = i - 73728;                         // i2 < 294912
        int part = i2 / 147456;                     // 0 = A (query side), 1 = B (doc side)
        int o = i2 % 147456;
        int j = o & 7, c = o >> 3;
        int lane = c & 63, st = c >> 6;             // st < 288
        int s = st/24, t = st%24;                   // s < 12, t < 24
        int n = t*16 + (lane&15), k = s*32 + ((lane>>4)&3)*8 + j;
        short v = f2bf(W1[(part*384 + k)*384 + n]);
        if (part) W1bT[o] = v; else W1aT[o] = v;
    } else {
        int o3 = i - 368640;                        // o3 < 768
        int j = o3 & 7, h = (o3>>3)&1, quad = (o3>>4)&3, s = o3>>6;
        int k = s*32 + quad*8 + j;
        W1cd[o3] = f2bf(W1[(768+h)*384 + k]);
    }
}

// ---------------------------------------------------------------- ab: MFMA GEMM
// blocks 0..255: Bws(bf16)[r0..r0+15] = doc rows @ W1b;  blocks 256..257: Aq(f32) = query @ W1a + b1.
__global__ __launch_bounds__(256)
void ab_kernel(const float* __restrict__ doc, const float* __restrict__ query,
               const short* __restrict__ W1aT, const short* __restrict__ W1bT,
               const float* __restrict__ b1,
               short* __restrict__ Bws, float* __restrict__ Aq){
    const int b = blockIdx.x, tid = threadIdx.x;
    const int w = tid >> 6, lane = tid & 63;
    const int cl = lane & 15, quad = lane >> 4;
    const float* src; const short* wt; int r0; bool isA;
    if (b < 256){ r0 = b*16;       src = doc;   wt = W1bT; isA = false; }
    else        { r0 = (b-256)*16; src = query; wt = W1aT; isA = true;  }

    f32x4 acc[6];
    #pragma unroll
    for (int t=0;t<6;t++) acc[t] = (f32x4){0.f,0.f,0.f,0.f};

    #pragma unroll
    for (int s=0;s<12;s++){
        const float* ap = src + (r0+cl)*384 + s*32 + quad*8;
        const f32x4 a0 = *(const f32x4*)ap;
        const f32x4 a1 = *(const f32x4*)(ap+4);
        bf16x8 af;
        #pragma unroll
        for (int j=0;j<4;j++){ af[j] = f2bf(a0[j]); af[4+j] = f2bf(a1[j]); }
        #pragma unroll
        for (int tt=0;tt<6;tt++){
            const bf16x8 bf_ = *(const bf16x8*)(wt + ((s*24 + w*6 + tt)*64 + lane)*8);
            acc[tt] = __builtin_amdgcn_mfma_f32_16x16x32_bf16(af, bf_, acc[tt], 0, 0, 0);
        }
    }
    // D layout: col=lane&15, row=quad*4+r
    #pragma unroll
    for (int tt=0;tt<6;tt++){
        const int col = (w*6+tt)*16 + cl;
        if (isA){
            const float b1v = b1[col];
            #pragma unroll
            for (int r=0;r<4;r++)
                Aq[(r0 + quad*4 + r)*384 + col] = acc[tt][r] + b1v;
        } else {
            #pragma unroll
            for (int r=0;r<4;r++)
                Bws[(r0 + quad*4 + r)*384 + col] = f2bf(acc[tt][r]);
        }
    }
}

// ---------------------------------------------------------------- dense scores + sparse copy
__global__ void dense_sparse_kernel(const float* __restrict__ query, const float* __restrict__ doc,
                                    const float* __restrict__ sparse, float* __restrict__ out_dense,
                                    float* __restrict__ out_sparse){
    __shared__ float ldsq[32*388];
    __shared__ float ldsd[16*388];
    const int tid = threadIdx.x, d0 = blockIdx.x*16;
    #pragma unroll
    for (int i=0;i<12;i++){ int idx = tid + i*256; int row = idx/96, c4 = idx%96;
        *(f32x4*)(ldsq + row*388 + c4*4) = *(const f32x4*)(query + row*384 + c4*4); }
    #pragma unroll
    for (int i=0;i<6;i++){ int idx = tid + i*256; int row = idx/96, c4 = idx%96;
        *(f32x4*)(ldsd + row*388 + c4*4) = *(const f32x4*)(doc + (d0+row)*384 + c4*4); }
    __syncthreads();
    const int q = tid>>3, dg = tid&7;
    float acc0 = 0.0f, acc1 = 0.0f;
    #pragma unroll 4
    for (int k=0;k<384;k++){
        float qv = ldsq[q*388 + k];
        acc0 += qv*ldsd[dg*388 + k];
        acc1 += qv*ldsd[(dg+8)*388 + k];
    }
    out_dense[q*4096 + d0 + dg]     = acc0;
    out_dense[q*4096 + d0 + dg + 8] = acc1;
    if (tid < 128){
        int qq = tid>>2, c4 = tid&3;
        *(f32x4*)(out_sparse + qq*4096 + d0 + c4*4) = *(const f32x4*)(sparse + qq*4096 + d0 + c4*4);
    }
}

// ---------------------------------------------------------------- main fused MLP kernel
// 256 blocks x 512 thr = 8 waves. Wave pair (2 waves) owns a 16-row group (16 q's of one doc);
// each wave of the pair computes 6 of 12 W2 n-tiles  -> acc=24 regs, ~100 total: fits the
// 128-reg budget the compiler insists on (rounds 2/5/6 all spilled at 12 tiles/wave).
// Layer-3 partials combined via 512 B LDS buffer.
__global__ __launch_bounds__(512, 2)
void main_kernel(const float* __restrict__ Aq, const short* __restrict__ Bws,
                 const short* __restrict__ W1cd,
                 const float* __restrict__ b2, const float* __restrict__ W3,
                 const float* __restrict__ b3, const float* __restrict__ sparse,
                 const short* __restrict__ W2Tt, const float* __restrict__ dense_in,
                 float* __restrict__ out_final){
    __shared__ short lw[73728];                      // 147,456 bytes
    __shared__ float pbuf[4][2][16];                 // +512 bytes
    const int tid = threadIdx.x;
    #pragma unroll
    for (int i=0;i<18;i++){                          // 9216 x 16B linear copy
        int idx = tid + i*512;
        *(bf16x8*)(lw + idx*8) = *(const bf16x8*)(W2Tt + idx*8);
    }
    __syncthreads();

    const int lane = tid & 63, w = tid >> 6;
    const int cl = lane & 15, quad = lane >> 4;
    const int pair = w >> 1, h = w & 1;              // pair: row-group within block; h: tile half
    float b2r[6], w3r[6];
    #pragma unroll
    for (int t=0;t<6;t++){ b2r[t] = b2[(h*6+t)*16 + cl]; w3r[t] = W3[(h*6+t)*16 + cl]; }
    const float b3v = b3[0];

    #pragma unroll 1
    for (int t4=0; t4<8; t4++){
        const int g = blockIdx.x*32 + t4*4 + pair;   // 16-row group id, g < 8192
        const int dcol = g >> 1;
        const int q0 = (g & 1)*16;
        const int q = q0 + cl;
        const float dsv = dense_in[q*4096 + dcol];
        const float ssv = sparse[q*4096 + dcol];

        f32x4 acc[6];
        #pragma unroll
        for (int t=0;t<6;t++) acc[t] = (f32x4){0.f,0.f,0.f,0.f};

        #pragma unroll
        for (int s=0;s<12;s++){
            const int k0 = s*32 + quad*8;
            // layer 1 for this kstep, directly in A-fragment layout (b1 pre-folded into Aq)
            const f32x4 a0   = *(const f32x4*)(Aq + q*384 + k0);
            const f32x4 a1   = *(const f32x4*)(Aq + q*384 + k0 + 4);
            const bf16x8 bw  = *(const bf16x8*)(Bws + dcol*384 + k0);
            const bf16x8 wcv = *(const bf16x8*)(W1cd + (s*4 + quad)*16);
            const bf16x8 wdv = *(const bf16x8*)(W1cd + (s*4 + quad)*16 + 8);
            bf16x8 fr;
            #pragma unroll
            for (int j=0;j<4;j++){
                float hh = a0[j] + bf2f(bw[j]) + dsv*bf2f(wcv[j]) + ssv*bf2f(wdv[j]);
                fr[j] = f2bf(fmaxf(hh, 0.0f));
            }
            #pragma unroll
            for (int j=0;j<4;j++){
                float hh = a1[j] + bf2f(bw[4+j]) + dsv*bf2f(wcv[4+j]) + ssv*bf2f(wdv[4+j]);
                fr[4+j] = f2bf(fmaxf(hh, 0.0f));
            }
            #pragma unroll
            for (int t=0;t<6;t++){
                const bf16x8 bfr = *(const bf16x8*)(lw + ((s*12 + h*6 + t)*64 + lane)*8);
                acc[t] = __builtin_amdgcn_mfma_f32_16x16x32_bf16(fr, bfr, acc[t], 0, 0, 0);
            }
        }

        // layer 3 partial over this wave's 6 tiles. D layout: col=lane&15 -> n, row=quad*4+r
        float p[4] = {0.f,0.f,0.f,0.f};
        #pragma unroll
        for (int t=0;t<6;t++){
            #pragma unroll
            for (int r=0;r<4;r++)
                p[r] += fmaxf(acc[t][r] + b2r[t], 0.0f) * w3r[t];
        }
        #pragma unroll
        for (int m=1; m<16; m<<=1){
            #pragma unroll
            for (int r=0;r<4;r++) p[r] += __shfl_xor(p[r], m);
        }
        if (cl == 0){
            #pragma unroll
            for (int r=0;r<4;r++) pbuf[pair][h][quad*4+r] = p[r];
        }
        __syncthreads();
        if (h == 0 && cl == 0){
            #pragma unroll
            for (int r=0;r<4;r++){
                int idx = quad*4 + r;
                int qq = q0 + idx;
                float logit = pbuf[pair][0][idx] + pbuf[pair][1][idx] + b3v;
                float wgt = 1.0f/(1.0f + __expf(-logit));
                float dd = dense_in[qq*4096 + dcol];
                float ss = sparse[qq*4096 + dcol];
                out_final[qq*4096 + dcol] = wgt*dd + (1.0f - wgt)*ss;
            }
        }
        __syncthreads();                             // protect pbuf before next iteration
    }
}

// ---------------------------------------------------------------- launch
extern "C" void kernel_launch(void* const* d_in, const int* in_sizes, int n_in,
                              void* d_out, int out_size, void* d_ws, size_t ws_size,
                              hipStream_t stream){
    const float* query  = (const float*)d_in[0];
    const float* doc    = (const float*)d_in[1];
    const float* sparse = (const float*)d_in[2];
    const float* W1     = (const float*)d_in[3];
    const float* b1     = (const float*)d_in[4];
    const float* W2     = (const float*)d_in[5];
    const float* b2     = (const float*)d_in[6];
    const float* W3     = (const float*)d_in[7];
    const float* b3     = (const float*)d_in[8];

    float* out_final  = (float*)d_out;                 // [32,4096]
    float* out_dense  = (float*)d_out + 131072;        // [32,4096]
    float* out_sparse = (float*)d_out + 262144;        // [32,4096]

    // workspace layout (16B-aligned), total 3,933,696 B
    short* Bws  = (short*)d_ws;                                   // 3,145,728 B  (bf16 [4096][384])
    float* Aq   = (float*)((char*)d_ws + 3145728);                //    49,152 B  (f32  [32][384])
    short* W2Tt = (short*)((char*)d_ws + 3194880);                //   147,456 B
    short* W1aT = (short*)((char*)d_ws + 3342336);                //   294,912 B
    short* W1bT = (short*)((char*)d_ws + 3637248);                //   294,912 B
    short* W1cd = (short*)((char*)d_ws + 3932160);                //     1,536 B

    hipLaunchKernelGGL(prep_kernel,         dim3(1443), dim3(256), 0, stream, W1, W2, W2Tt, W1aT, W1bT, W1cd);
    hipLaunchKernelGGL(ab_kernel,           dim3(258),  dim3(256), 0, stream, doc, query, W1aT, W1bT, b1, Bws, Aq);
    hipLaunchKernelGGL(dense_sparse_kernel, dim3(256),  dim3(256), 0, stream, query, doc, sparse, out_dense, out_sparse);
    hipLaunchKernelGGL(main_kernel,         dim3(256),  dim3(512), 0, stream,
                       Aq, Bws, W1cd, b2, W3, b3, sparse, W2Tt, out_dense, out_final);
}

// Round 8
// 178.396 us; speedup vs baseline: 3.9567x; 1.8944x over previous
//
#include <hip/hip_runtime.h>
#include <hip/hip_bf16.h>

typedef __attribute__((ext_vector_type(4))) float f32x4;
typedef __attribute__((ext_vector_type(8))) short bf16x8;

__device__ __forceinline__ short f2bf(float x){
    __hip_bfloat16 h = __float2bfloat16(x);
    return __builtin_bit_cast(short, h);
}
__device__ __forceinline__ float bf2f(short x){
    unsigned int u = ((unsigned int)(unsigned short)x) << 16;
    return __builtin_bit_cast(float, u);
}

// ---------------------------------------------------------------- prep: tiled bf16 weights
// W2Tt  [9216 chunks of 8]:  chunk=(s*12+t)*64+lane -> W2[k][n],  n=t*16+(lane&15), k=s*32+((lane>>4)&3)*8+j
// W1aT/W1bT [147456 each]:   chunk=(s*24+t)*64+lane -> W1[k(+384)][n], s<12, t<24
// W1cd  [768]: (s*4+quad)*16 + h*8 + j -> bf16 of W1[768+h][s*32+quad*8+j]
__global__ void prep_kernel(const float* __restrict__ W1, const float* __restrict__ W2,
                            short* __restrict__ W2Tt, short* __restrict__ W1aT,
                            short* __restrict__ W1bT, short* __restrict__ W1cd){
    int i = blockIdx.x*256 + threadIdx.x;           // 369408 total = 1443*256 exactly
    if (i < 73728){
        int j = i & 7, c = i >> 3;
        int lane = c & 63, st = c >> 6;             // st < 144
        int s = st/12, t = st%12;
        int n = t*16 + (lane&15), k = s*32 + ((lane>>4)&3)*8 + j;
        W2Tt[i] = f2bf(W2[k*192 + n]);
    } else if (i < 368640){
        int i2 = i - 73728;                         // i2 < 294912
        int part = i2 / 147456;                     // 0 = A (query side), 1 = B (doc side)
        int o = i2 % 147456;
        int j = o & 7, c = o >> 3;
        int lane = c & 63, st = c >> 6;             // st < 288
        int s = st/24, t = st%24;                   // s < 12, t < 24
        int n = t*16 + (lane&15), k = s*32 + ((lane>>4)&3)*8 + j;
        short v = f2bf(W1[(part*384 + k)*384 + n]);
        if (part) W1bT[o] = v; else W1aT[o] = v;
    } else {
        int o3 = i - 368640;                        // o3 < 768
        int j = o3 & 7, h = (o3>>3)&1, quad = (o3>>4)&3, s = o3>>6;
        int k = s*32 + quad*8 + j;
        W1cd[o3] = f2bf(W1[(768+h)*384 + k]);
    }
}

// ---------------------------------------------------------------- ab: MFMA GEMM
// blocks 0..255: Bws(bf16)[r0..r0+15] = doc rows @ W1b;  blocks 256..257: Aq(f32) = query @ W1a + b1.
__global__ __launch_bounds__(256)
void ab_kernel(const float* __restrict__ doc, const float* __restrict__ query,
               const short* __restrict__ W1aT, const short* __restrict__ W1bT,
               const float* __restrict__ b1,
               short* __restrict__ Bws, float* __restrict__ Aq){
    const int b = blockIdx.x, tid = threadIdx.x;
    const int w = tid >> 6, lane = tid & 63;
    const int cl = lane & 15, quad = lane >> 4;
    const float* src; const short* wt; int r0; bool isA;
    if (b < 256){ r0 = b*16;       src = doc;   wt = W1bT; isA = false; }
    else        { r0 = (b-256)*16; src = query; wt = W1aT; isA = true;  }

    f32x4 acc[6];
    #pragma unroll
    for (int t=0;t<6;t++) acc[t] = (f32x4){0.f,0.f,0.f,0.f};

    #pragma unroll 1
    for (int s=0;s<12;s++){
        const float* ap = src + (r0+cl)*384 + s*32 + quad*8;
        const f32x4 a0 = *(const f32x4*)ap;
        const f32x4 a1 = *(const f32x4*)(ap+4);
        bf16x8 af;
        #pragma unroll
        for (int j=0;j<4;j++){ af[j] = f2bf(a0[j]); af[4+j] = f2bf(a1[j]); }
        #pragma unroll
        for (int tt=0;tt<6;tt++){
            const bf16x8 bf_ = *(const bf16x8*)(wt + ((s*24 + w*6 + tt)*64 + lane)*8);
            acc[tt] = __builtin_amdgcn_mfma_f32_16x16x32_bf16(af, bf_, acc[tt], 0, 0, 0);
        }
    }
    // D layout: col=lane&15, row=quad*4+r
    #pragma unroll
    for (int tt=0;tt<6;tt++){
        const int col = (w*6+tt)*16 + cl;
        if (isA){
            const float b1v = b1[col];
            #pragma unroll
            for (int r=0;r<4;r++)
                Aq[(r0 + quad*4 + r)*384 + col] = acc[tt][r] + b1v;
        } else {
            #pragma unroll
            for (int r=0;r<4;r++)
                Bws[(r0 + quad*4 + r)*384 + col] = f2bf(acc[tt][r]);
        }
    }
}

// ---------------------------------------------------------------- dense scores + sparse copy
__global__ void dense_sparse_kernel(const float* __restrict__ query, const float* __restrict__ doc,
                                    const float* __restrict__ sparse, float* __restrict__ out_dense,
                                    float* __restrict__ out_sparse){
    __shared__ float ldsq[32*388];
    __shared__ float ldsd[16*388];
    const int tid = threadIdx.x, d0 = blockIdx.x*16;
    #pragma unroll
    for (int i=0;i<12;i++){ int idx = tid + i*256; int row = idx/96, c4 = idx%96;
        *(f32x4*)(ldsq + row*388 + c4*4) = *(const f32x4*)(query + row*384 + c4*4); }
    #pragma unroll
    for (int i=0;i<6;i++){ int idx = tid + i*256; int row = idx/96, c4 = idx%96;
        *(f32x4*)(ldsd + row*388 + c4*4) = *(const f32x4*)(doc + (d0+row)*384 + c4*4); }
    __syncthreads();
    const int q = tid>>3, dg = tid&7;
    float acc0 = 0.0f, acc1 = 0.0f;
    #pragma unroll 4
    for (int k=0;k<384;k++){
        float qv = ldsq[q*388 + k];
        acc0 += qv*ldsd[dg*388 + k];
        acc1 += qv*ldsd[(dg+8)*388 + k];
    }
    out_dense[q*4096 + d0 + dg]     = acc0;
    out_dense[q*4096 + d0 + dg + 8] = acc1;
    if (tid < 128){
        int qq = tid>>2, c4 = tid&3;
        *(f32x4*)(out_sparse + qq*4096 + d0 + c4*4) = *(const f32x4*)(sparse + qq*4096 + d0 + c4*4);
    }
}

// ---------------------------------------------------------------- main fused MLP kernel
// 256 blocks x 512 thr = 8 waves = 4 wave pairs. A group = one doc column x all 32 queries.
// Each pair owns one group per iteration (4 iters: 16 docs/block); within the pair each wave
// computes 6 of 12 W2 n-tiles for BOTH 16-row A-fragments -> each bfr LDS read feeds 2 MFMAs
// (halves LDS traffic vs round 7). K-loop is NOT unrolled (unroll 1): keeps live set < 128
// VGPRs -- rounds 5-7 showed the allocator pins 128 and full unroll spills ~300MB-1.1GB.
__global__ __launch_bounds__(512, 2)
void main_kernel(const float* __restrict__ Aq, const short* __restrict__ Bws,
                 const short* __restrict__ W1cd,
                 const float* __restrict__ b2, const float* __restrict__ W3,
                 const float* __restrict__ b3, const float* __restrict__ sparse,
                 const short* __restrict__ W2Tt, const float* __restrict__ dense_in,
                 float* __restrict__ out_final){
    __shared__ short lw[73728];                      // 147,456 bytes
    __shared__ float pbuf[4][2][2][16];              // +1024 bytes
    const int tid = threadIdx.x;
    #pragma unroll
    for (int i=0;i<18;i++){                          // 9216 x 16B linear copy
        int idx = tid + i*512;
        *(bf16x8*)(lw + idx*8) = *(const bf16x8*)(W2Tt + idx*8);
    }
    __syncthreads();

    const int lane = tid & 63, w = tid >> 6;
    const int cl = lane & 15, quad = lane >> 4;
    const int pair = w >> 1, h = w & 1;              // pair: group within block; h: tile half
    float b2r[6], w3r[6];
    #pragma unroll
    for (int t=0;t<6;t++){ b2r[t] = b2[(h*6+t)*16 + cl]; w3r[t] = W3[(h*6+t)*16 + cl]; }
    const float b3v = b3[0];

    #pragma unroll 1
    for (int t4=0; t4<4; t4++){
        const int dcol = blockIdx.x*16 + t4*4 + pair;    // doc column, < 4096
        const float dsv0 = dense_in[cl*4096 + dcol];
        const float ssv0 = sparse[cl*4096 + dcol];
        const float dsv1 = dense_in[(16+cl)*4096 + dcol];
        const float ssv1 = sparse[(16+cl)*4096 + dcol];

        f32x4 acc0[6], acc1[6];
        #pragma unroll
        for (int t=0;t<6;t++){ acc0[t] = (f32x4){0.f,0.f,0.f,0.f}; acc1[t] = (f32x4){0.f,0.f,0.f,0.f}; }

        #pragma unroll 1
        for (int s=0;s<12;s++){
            const int k0 = s*32 + quad*8;
            const bf16x8 bw  = *(const bf16x8*)(Bws + dcol*384 + k0);
            const bf16x8 wcv = *(const bf16x8*)(W1cd + (s*4 + quad)*16);
            const bf16x8 wdv = *(const bf16x8*)(W1cd + (s*4 + quad)*16 + 8);
            // rows 0..15 (q = cl)
            const f32x4 a0 = *(const f32x4*)(Aq + cl*384 + k0);
            const f32x4 a1 = *(const f32x4*)(Aq + cl*384 + k0 + 4);
            bf16x8 fr0;
            #pragma unroll
            for (int j=0;j<4;j++){
                float hh = a0[j] + bf2f(bw[j]) + dsv0*bf2f(wcv[j]) + ssv0*bf2f(wdv[j]);
                fr0[j] = f2bf(fmaxf(hh, 0.0f));
                float hh2 = a1[j] + bf2f(bw[4+j]) + dsv0*bf2f(wcv[4+j]) + ssv0*bf2f(wdv[4+j]);
                fr0[4+j] = f2bf(fmaxf(hh2, 0.0f));
            }
            // rows 16..31 (q = 16+cl)
            const f32x4 c0 = *(const f32x4*)(Aq + (16+cl)*384 + k0);
            const f32x4 c1 = *(const f32x4*)(Aq + (16+cl)*384 + k0 + 4);
            bf16x8 fr1;
            #pragma unroll
            for (int j=0;j<4;j++){
                float hh = c0[j] + bf2f(bw[j]) + dsv1*bf2f(wcv[j]) + ssv1*bf2f(wdv[j]);
                fr1[j] = f2bf(fmaxf(hh, 0.0f));
                float hh2 = c1[j] + bf2f(bw[4+j]) + dsv1*bf2f(wcv[4+j]) + ssv1*bf2f(wdv[4+j]);
                fr1[4+j] = f2bf(fmaxf(hh2, 0.0f));
            }
            #pragma unroll
            for (int t=0;t<6;t++){
                const bf16x8 bfr = *(const bf16x8*)(lw + ((s*12 + h*6 + t)*64 + lane)*8);
                acc0[t] = __builtin_amdgcn_mfma_f32_16x16x32_bf16(fr0, bfr, acc0[t], 0, 0, 0);
                acc1[t] = __builtin_amdgcn_mfma_f32_16x16x32_bf16(fr1, bfr, acc1[t], 0, 0, 0);
            }
        }

        // layer 3 partial over this wave's 6 tiles. D layout: col=lane&15 -> n, row=quad*4+r
        float p0[4] = {0.f,0.f,0.f,0.f}, p1[4] = {0.f,0.f,0.f,0.f};
        #pragma unroll
        for (int t=0;t<6;t++){
            #pragma unroll
            for (int r=0;r<4;r++){
                p0[r] += fmaxf(acc0[t][r] + b2r[t], 0.0f) * w3r[t];
                p1[r] += fmaxf(acc1[t][r] + b2r[t], 0.0f) * w3r[t];
            }
        }
        #pragma unroll
        for (int m=1; m<16; m<<=1){
            #pragma unroll
            for (int r=0;r<4;r++){ p0[r] += __shfl_xor(p0[r], m); p1[r] += __shfl_xor(p1[r], m); }
        }
        if (cl == 0){
            #pragma unroll
            for (int r=0;r<4;r++){
                pbuf[pair][h][0][quad*4+r] = p0[r];
                pbuf[pair][h][1][quad*4+r] = p1[r];
            }
        }
        __syncthreads();
        if (h == 0 && cl == 0){
            #pragma unroll
            for (int m=0;m<2;m++){
                #pragma unroll
                for (int r=0;r<4;r++){
                    int idx = quad*4 + r;
                    int qq = m*16 + idx;
                    float logit = pbuf[pair][0][m][idx] + pbuf[pair][1][m][idx] + b3v;
                    float wgt = 1.0f/(1.0f + __expf(-logit));
                    float dd = dense_in[qq*4096 + dcol];
                    float ss = sparse[qq*4096 + dcol];
                    out_final[qq*4096 + dcol] = wgt*dd + (1.0f - wgt)*ss;
                }
            }
        }
        __syncthreads();                             // protect pbuf before next iteration
    }
}

// ---------------------------------------------------------------- launch
extern "C" void kernel_launch(void* const* d_in, const int* in_sizes, int n_in,
                              void* d_out, int out_size, void* d_ws, size_t ws_size,
                              hipStream_t stream){
    const float* query  = (const float*)d_in[0];
    const float* doc    = (const float*)d_in[1];
    const float* sparse = (const float*)d_in[2];
    const float* W1     = (const float*)d_in[3];
    const float* b1     = (const float*)d_in[4];
    const float* W2     = (const float*)d_in[5];
    const float* b2     = (const float*)d_in[6];
    const float* W3     = (const float*)d_in[7];
    const float* b3     = (const float*)d_in[8];

    float* out_final  = (float*)d_out;                 // [32,4096]
    float* out_dense  = (float*)d_out + 131072;        // [32,4096]
    float* out_sparse = (float*)d_out + 262144;        // [32,4096]

    // workspace layout (16B-aligned), total 3,933,696 B
    short* Bws  = (short*)d_ws;                                   // 3,145,728 B  (bf16 [4096][384])
    float* Aq   = (float*)((char*)d_ws + 3145728);                //    49,152 B  (f32  [32][384])
    short* W2Tt = (short*)((char*)d_ws + 3194880);                //   147,456 B
    short* W1aT = (short*)((char*)d_ws + 3342336);                //   294,912 B
    short* W1bT = (short*)((char*)d_ws + 3637248);                //   294,912 B
    short* W1cd = (short*)((char*)d_ws + 3932160);                //     1,536 B

    hipLaunchKernelGGL(prep_kernel,         dim3(1443), dim3(256), 0, stream, W1, W2, W2Tt, W1aT, W1bT, W1cd);
    hipLaunchKernelGGL(ab_kernel,           dim3(258),  dim3(256), 0, stream, doc, query, W1aT, W1bT, b1, Bws, Aq);
    hipLaunchKernelGGL(dense_sparse_kernel, dim3(256),  dim3(256), 0, stream, query, doc, sparse, out_dense, out_sparse);
    hipLaunchKernelGGL(main_kernel,         dim3(256),  dim3(512), 0, stream,
                       Aq, Bws, W1cd, b2, W3, b3, sparse, W2Tt, out_dense, out_final);
}

// Round 9
// 169.526 us; speedup vs baseline: 4.1637x; 1.0523x over previous
//
#include <hip/hip_runtime.h>
#include <hip/hip_bf16.h>

typedef __attribute__((ext_vector_type(4))) float f32x4;
typedef __attribute__((ext_vector_type(8))) short bf16x8;

__device__ __forceinline__ short f2bf(float x){
    __hip_bfloat16 h = __float2bfloat16(x);
    return __builtin_bit_cast(short, h);
}
__device__ __forceinline__ float bf2f(short x){
    unsigned int u = ((unsigned int)(unsigned short)x) << 16;
    return __builtin_bit_cast(float, u);
}

// ---------------------------------------------------------------- pre: dense scores + sparse copy + AB GEMM
// blocks 0..255   : dense_sparse body (16 docs x 32 q each)
// blocks 256..511 : Bws(bf16)[16 doc rows] = doc @ W1b   (W1 read directly, wave-coalesced gather)
// blocks 512..513 : Aq(f32)[16 q rows]     = query @ W1a + b1
__global__ __launch_bounds__(256)
void pre_kernel(const float* __restrict__ query, const float* __restrict__ doc,
                const float* __restrict__ sparse, const float* __restrict__ W1,
                const float* __restrict__ b1,
                float* __restrict__ out_dense, float* __restrict__ out_sparse,
                short* __restrict__ Bws, float* __restrict__ Aq){
    __shared__ float ldsq[32*388];
    __shared__ float ldsd[16*388];
    const int b = blockIdx.x, tid = threadIdx.x;

    if (b < 256){
        // ---- dense scores + sparse passthrough (unchanged logic)
        const int d0 = b*16;
        #pragma unroll
        for (int i=0;i<12;i++){ int idx = tid + i*256; int row = idx/96, c4 = idx%96;
            *(f32x4*)(ldsq + row*388 + c4*4) = *(const f32x4*)(query + row*384 + c4*4); }
        #pragma unroll
        for (int i=0;i<6;i++){ int idx = tid + i*256; int row = idx/96, c4 = idx%96;
            *(f32x4*)(ldsd + row*388 + c4*4) = *(const f32x4*)(doc + (d0+row)*384 + c4*4); }
        __syncthreads();
        const int q = tid>>3, dg = tid&7;
        float acc0 = 0.0f, acc1 = 0.0f;
        #pragma unroll 4
        for (int k=0;k<384;k++){
            float qv = ldsq[q*388 + k];
            acc0 += qv*ldsd[dg*388 + k];
            acc1 += qv*ldsd[(dg+8)*388 + k];
        }
        out_dense[q*4096 + d0 + dg]     = acc0;
        out_dense[q*4096 + d0 + dg + 8] = acc1;
        if (tid < 128){
            int qq = tid>>2, c4 = tid&3;
            *(f32x4*)(out_sparse + qq*4096 + d0 + c4*4) = *(const f32x4*)(sparse + qq*4096 + d0 + c4*4);
        }
    } else {
        // ---- AB GEMM, W1 read directly (B-frag: reg j = W1[(s*32+quad*8+j)][col])
        const int bb = b - 256;
        const int w = tid >> 6, lane = tid & 63;
        const int cl = lane & 15, quad = lane >> 4;
        const float* src; const float* wrow; int r0; bool isA;
        if (bb < 256){ r0 = bb*16;       src = doc;   wrow = W1 + 384*384; isA = false; }
        else         { r0 = (bb-256)*16; src = query; wrow = W1;           isA = true;  }

        f32x4 acc[6];
        #pragma unroll
        for (int t=0;t<6;t++) acc[t] = (f32x4){0.f,0.f,0.f,0.f};

        #pragma unroll 1
        for (int s=0;s<12;s++){
            const float* ap = src + (r0+cl)*384 + s*32 + quad*8;
            const f32x4 a0 = *(const f32x4*)ap;
            const f32x4 a1 = *(const f32x4*)(ap+4);
            bf16x8 af;
            #pragma unroll
            for (int j=0;j<4;j++){ af[j] = f2bf(a0[j]); af[4+j] = f2bf(a1[j]); }
            const float* wk = wrow + (s*32 + quad*8)*384;
            #pragma unroll
            for (int tt=0;tt<6;tt++){
                const int col = (w*6+tt)*16 + cl;
                bf16x8 bf_;
                #pragma unroll
                for (int j=0;j<8;j++) bf_[j] = f2bf(wk[j*384 + col]);
                acc[tt] = __builtin_amdgcn_mfma_f32_16x16x32_bf16(af, bf_, acc[tt], 0, 0, 0);
            }
        }
        // D layout: col=lane&15, row=quad*4+r
        #pragma unroll
        for (int tt=0;tt<6;tt++){
            const int col = (w*6+tt)*16 + cl;
            if (isA){
                const float b1v = b1[col];
                #pragma unroll
                for (int r=0;r<4;r++)
                    Aq[(r0 + quad*4 + r)*384 + col] = acc[tt][r] + b1v;
            } else {
                #pragma unroll
                for (int r=0;r<4;r++)
                    Bws[(r0 + quad*4 + r)*384 + col] = f2bf(acc[tt][r]);
            }
        }
    }
}

// ---------------------------------------------------------------- main fused MLP kernel
// 256 blocks x 1024 thr = 16 waves = 4 waves/SIMD (vs 2 in round 8: doubles latency hiding;
// LDS 149.5 KB still allows the 1 block/CU we get anyway). Wave pair owns one doc column x
// all 32 queries; each wave computes 6 of 12 W2 n-tiles for both 16-row A-fragments.
// W2 is staged tiled into LDS by the block itself (prep kernel eliminated).
// K-loop unroll 1 (128-reg budget; rounds 5-7 spilled when unrolled) + 1-deep Bws prefetch.
__global__ __launch_bounds__(1024)
void main_kernel(const float* __restrict__ Aq, const short* __restrict__ Bws,
                 const float* __restrict__ W1, const float* __restrict__ W2,
                 const float* __restrict__ b2, const float* __restrict__ W3,
                 const float* __restrict__ b3, const float* __restrict__ sparse,
                 const float* __restrict__ dense_in, float* __restrict__ out_final){
    __shared__ short lw[73728];                      // 147,456 B
    __shared__ float pbuf[8][2][2][16];              // + 2,048 B
    const int tid = threadIdx.x;
    // stage W2 -> LDS in MFMA-tile order: chunk c=(s*12+t)*64+lane_c, reg j = W2[k][n],
    // n = t*16+(lane_c&15), k = s*32+((lane_c>>4)&3)*8+j. 9 chunks per thread.
    #pragma unroll
    for (int i=0;i<9;i++){
        int c = tid + i*1024;
        int lane_c = c & 63, st = c >> 6;
        int s = st/12, t = st%12;
        int n = t*16 + (lane_c&15), kb = s*32 + ((lane_c>>4)&3)*8;
        bf16x8 v;
        #pragma unroll
        for (int j=0;j<8;j++) v[j] = f2bf(W2[(kb+j)*192 + n]);
        *(bf16x8*)(lw + c*8) = v;
    }
    __syncthreads();

    const int lane = tid & 63, w = tid >> 6;
    const int cl = lane & 15, quad = lane >> 4;
    const int pair = w >> 1, h = w & 1;              // pair 0..7; h: tile half
    const float b3v = b3[0];
    const float* w1c = W1 + 768*384;
    const float* w1d = W1 + 769*384;

    #pragma unroll 1
    for (int t4=0; t4<2; t4++){
        const int dcol = blockIdx.x*16 + t4*8 + pair;    // doc column, < 4096
        const float dsv0 = dense_in[cl*4096 + dcol];
        const float ssv0 = sparse[cl*4096 + dcol];
        const float dsv1 = dense_in[(16+cl)*4096 + dcol];
        const float ssv1 = sparse[(16+cl)*4096 + dcol];

        f32x4 acc0[6], acc1[6];
        #pragma unroll
        for (int t=0;t<6;t++){ acc0[t] = (f32x4){0.f,0.f,0.f,0.f}; acc1[t] = (f32x4){0.f,0.f,0.f,0.f}; }

        bf16x8 bw_c = *(const bf16x8*)(Bws + dcol*384 + quad*8);
        #pragma unroll 1
        for (int s=0;s<12;s++){
            const int k0 = s*32 + quad*8;
            const int k0n = (s < 11) ? (k0 + 32) : (quad*8);     // dummy wrap on last iter
            const bf16x8 bw_n = *(const bf16x8*)(Bws + dcol*384 + k0n);
            const f32x4 a0 = *(const f32x4*)(Aq + cl*384 + k0);
            const f32x4 a1 = *(const f32x4*)(Aq + cl*384 + k0 + 4);
            const f32x4 c0 = *(const f32x4*)(Aq + (16+cl)*384 + k0);
            const f32x4 c1 = *(const f32x4*)(Aq + (16+cl)*384 + k0 + 4);
            const f32x4 wc0 = *(const f32x4*)(w1c + k0);
            const f32x4 wc1 = *(const f32x4*)(w1c + k0 + 4);
            const f32x4 wd0 = *(const f32x4*)(w1d + k0);
            const f32x4 wd1 = *(const f32x4*)(w1d + k0 + 4);
            bf16x8 fr0, fr1;
            #pragma unroll
            for (int j=0;j<4;j++){
                float g0 = bf2f(bw_c[j]), g1 = bf2f(bw_c[4+j]);
                float h0 = a0[j] + g0 + dsv0*wc0[j] + ssv0*wd0[j];
                float h1 = a1[j] + g1 + dsv0*wc1[j] + ssv0*wd1[j];
                fr0[j]   = f2bf(fmaxf(h0, 0.0f));
                fr0[4+j] = f2bf(fmaxf(h1, 0.0f));
                float h2 = c0[j] + g0 + dsv1*wc0[j] + ssv1*wd0[j];
                float h3 = c1[j] + g1 + dsv1*wc1[j] + ssv1*wd1[j];
                fr1[j]   = f2bf(fmaxf(h2, 0.0f));
                fr1[4+j] = f2bf(fmaxf(h3, 0.0f));
            }
            #pragma unroll
            for (int t=0;t<6;t++){
                const bf16x8 bfr = *(const bf16x8*)(lw + ((s*12 + h*6 + t)*64 + lane)*8);
                acc0[t] = __builtin_amdgcn_mfma_f32_16x16x32_bf16(fr0, bfr, acc0[t], 0, 0, 0);
                acc1[t] = __builtin_amdgcn_mfma_f32_16x16x32_bf16(fr1, bfr, acc1[t], 0, 0, 0);
            }
            bw_c = bw_n;
        }

        // layer 3 partial over this wave's 6 tiles. D layout: col=lane&15 -> n, row=quad*4+r
        float p0[4] = {0.f,0.f,0.f,0.f}, p1[4] = {0.f,0.f,0.f,0.f};
        #pragma unroll
        for (int t=0;t<6;t++){
            const float b2v = b2[(h*6+t)*16 + cl];
            const float w3v = W3[(h*6+t)*16 + cl];
            #pragma unroll
            for (int r=0;r<4;r++){
                p0[r] += fmaxf(acc0[t][r] + b2v, 0.0f) * w3v;
                p1[r] += fmaxf(acc1[t][r] + b2v, 0.0f) * w3v;
            }
        }
        #pragma unroll
        for (int m=1; m<16; m<<=1){
            #pragma unroll
            for (int r=0;r<4;r++){ p0[r] += __shfl_xor(p0[r], m); p1[r] += __shfl_xor(p1[r], m); }
        }
        if (cl == 0){
            #pragma unroll
            for (int r=0;r<4;r++){
                pbuf[pair][h][0][quad*4+r] = p0[r];
                pbuf[pair][h][1][quad*4+r] = p1[r];
            }
        }
        __syncthreads();
        if (h == 0 && cl == 0){
            #pragma unroll
            for (int m=0;m<2;m++){
                #pragma unroll
                for (int r=0;r<4;r++){
                    int idx = quad*4 + r;
                    int qq = m*16 + idx;
                    float logit = pbuf[pair][0][m][idx] + pbuf[pair][1][m][idx] + b3v;
                    float wgt = 1.0f/(1.0f + __expf(-logit));
                    float dd = dense_in[qq*4096 + dcol];
                    float ss = sparse[qq*4096 + dcol];
                    out_final[qq*4096 + dcol] = wgt*dd + (1.0f - wgt)*ss;
                }
            }
        }
        __syncthreads();                             // protect pbuf before next iteration
    }
}

// ---------------------------------------------------------------- launch
extern "C" void kernel_launch(void* const* d_in, const int* in_sizes, int n_in,
                              void* d_out, int out_size, void* d_ws, size_t ws_size,
                              hipStream_t stream){
    const float* query  = (const float*)d_in[0];
    const float* doc    = (const float*)d_in[1];
    const float* sparse = (const float*)d_in[2];
    const float* W1     = (const float*)d_in[3];
    const float* b1     = (const float*)d_in[4];
    const float* W2     = (const float*)d_in[5];
    const float* b2     = (const float*)d_in[6];
    const float* W3     = (const float*)d_in[7];
    const float* b3     = (const float*)d_in[8];

    float* out_final  = (float*)d_out;                 // [32,4096]
    float* out_dense  = (float*)d_out + 131072;        // [32,4096]
    float* out_sparse = (float*)d_out + 262144;        // [32,4096]

    // workspace layout (16B-aligned), total 3,194,880 B
    short* Bws = (short*)d_ws;                                    // 3,145,728 B  (bf16 [4096][384])
    float* Aq  = (float*)((char*)d_ws + 3145728);                 //    49,152 B  (f32  [32][384])

    hipLaunchKernelGGL(pre_kernel,  dim3(514), dim3(256),  0, stream,
                       query, doc, sparse, W1, b1, out_dense, out_sparse, Bws, Aq);
    hipLaunchKernelGGL(main_kernel, dim3(256), dim3(1024), 0, stream,
                       Aq, Bws, W1, W2, b2, W3, b3, sparse, out_dense, out_final);
}

// Round 10
// 143.260 us; speedup vs baseline: 4.9271x; 1.1834x over previous
//
#include <hip/hip_runtime.h>
#include <hip/hip_bf16.h>

typedef __attribute__((ext_vector_type(4))) float f32x4;
typedef __attribute__((ext_vector_type(8))) short bf16x8;

__device__ __forceinline__ short f2bf(float x){
    __hip_bfloat16 h = __float2bfloat16(x);
    return __builtin_bit_cast(short, h);
}
__device__ __forceinline__ float bf2f(short x){
    unsigned int u = ((unsigned int)(unsigned short)x) << 16;
    return __builtin_bit_cast(float, u);
}

// ---------------------------------------------------------------- pre: dense scores + sparse copy + AB GEMM
// (unchanged from round 9 -- known good; will be profiled next round once main stops dominating)
__global__ __launch_bounds__(256)
void pre_kernel(const float* __restrict__ query, const float* __restrict__ doc,
                const float* __restrict__ sparse, const float* __restrict__ W1,
                const float* __restrict__ b1,
                float* __restrict__ out_dense, float* __restrict__ out_sparse,
                short* __restrict__ Bws, float* __restrict__ Aq){
    __shared__ float ldsq[32*388];
    __shared__ float ldsd[16*388];
    const int b = blockIdx.x, tid = threadIdx.x;

    if (b < 256){
        const int d0 = b*16;
        #pragma unroll
        for (int i=0;i<12;i++){ int idx = tid + i*256; int row = idx/96, c4 = idx%96;
            *(f32x4*)(ldsq + row*388 + c4*4) = *(const f32x4*)(query + row*384 + c4*4); }
        #pragma unroll
        for (int i=0;i<6;i++){ int idx = tid + i*256; int row = idx/96, c4 = idx%96;
            *(f32x4*)(ldsd + row*388 + c4*4) = *(const f32x4*)(doc + (d0+row)*384 + c4*4); }
        __syncthreads();
        const int q = tid>>3, dg = tid&7;
        float acc0 = 0.0f, acc1 = 0.0f;
        #pragma unroll 4
        for (int k=0;k<384;k++){
            float qv = ldsq[q*388 + k];
            acc0 += qv*ldsd[dg*388 + k];
            acc1 += qv*ldsd[(dg+8)*388 + k];
        }
        out_dense[q*4096 + d0 + dg]     = acc0;
        out_dense[q*4096 + d0 + dg + 8] = acc1;
        if (tid < 128){
            int qq = tid>>2, c4 = tid&3;
            *(f32x4*)(out_sparse + qq*4096 + d0 + c4*4) = *(const f32x4*)(sparse + qq*4096 + d0 + c4*4);
        }
    } else {
        const int bb = b - 256;
        const int w = tid >> 6, lane = tid & 63;
        const int cl = lane & 15, quad = lane >> 4;
        const float* src; const float* wrow; int r0; bool isA;
        if (bb < 256){ r0 = bb*16;       src = doc;   wrow = W1 + 384*384; isA = false; }
        else         { r0 = (bb-256)*16; src = query; wrow = W1;           isA = true;  }

        f32x4 acc[6];
        #pragma unroll
        for (int t=0;t<6;t++) acc[t] = (f32x4){0.f,0.f,0.f,0.f};

        #pragma unroll 1
        for (int s=0;s<12;s++){
            const float* ap = src + (r0+cl)*384 + s*32 + quad*8;
            const f32x4 a0 = *(const f32x4*)ap;
            const f32x4 a1 = *(const f32x4*)(ap+4);
            bf16x8 af;
            #pragma unroll
            for (int j=0;j<4;j++){ af[j] = f2bf(a0[j]); af[4+j] = f2bf(a1[j]); }
            const float* wk = wrow + (s*32 + quad*8)*384;
            #pragma unroll
            for (int tt=0;tt<6;tt++){
                const int col = (w*6+tt)*16 + cl;
                bf16x8 bf_;
                #pragma unroll
                for (int j=0;j<8;j++) bf_[j] = f2bf(wk[j*384 + col]);
                acc[tt] = __builtin_amdgcn_mfma_f32_16x16x32_bf16(af, bf_, acc[tt], 0, 0, 0);
            }
        }
        #pragma unroll
        for (int tt=0;tt<6;tt++){
            const int col = (w*6+tt)*16 + cl;
            if (isA){
                const float b1v = b1[col];
                #pragma unroll
                for (int r=0;r<4;r++)
                    Aq[(r0 + quad*4 + r)*384 + col] = acc[tt][r] + b1v;
            } else {
                #pragma unroll
                for (int r=0;r<4;r++)
                    Bws[(r0 + quad*4 + r)*384 + col] = f2bf(acc[tt][r]);
            }
        }
    }
}

// ---------------------------------------------------------------- main fused MLP kernel
// 256 blocks x 512 thr (128-VGPR budget -- round 9 showed 1024 thr cuts it to 64 and spills).
// Wave pair owns one doc column; wave h handles rows h*16..h*16+15 with ALL 12 n-tiles:
// layer-1 fragments built exactly once chip-wide (round 8 duplicated x2), and each wave owns
// a complete logit -> epilogue has no LDS combine and ZERO barriers after staging.
// K-loop unroll 1 + full prefetch of next-kstep Bws/Aq loads (hides ~200-400cyc L2 latency
// under the ~360cyc fr-build+MFMA body at only 2 waves/SIMD).
__global__ __launch_bounds__(512, 2)
void main_kernel(const float* __restrict__ Aq, const short* __restrict__ Bws,
                 const float* __restrict__ W1, const float* __restrict__ W2,
                 const float* __restrict__ b2, const float* __restrict__ W3,
                 const float* __restrict__ b3, const float* __restrict__ sparse,
                 const float* __restrict__ dense_in, float* __restrict__ out_final){
    __shared__ short lw[73728];                      // 147,456 B
    const int tid = threadIdx.x;
    // stage W2 -> LDS in MFMA-tile order: chunk c=(s*12+t)*64+lane_c, reg j = W2[k][n]
    #pragma unroll
    for (int i=0;i<18;i++){
        int c = tid + i*512;
        int lane_c = c & 63, st = c >> 6;
        int s = st/12, t = st%12;
        int n = t*16 + (lane_c&15), kb = s*32 + ((lane_c>>4)&3)*8;
        bf16x8 v;
        #pragma unroll
        for (int j=0;j<8;j++) v[j] = f2bf(W2[(kb+j)*192 + n]);
        *(bf16x8*)(lw + c*8) = v;
    }
    __syncthreads();                                 // only barrier in the kernel

    const int lane = tid & 63, w = tid >> 6;
    const int cl = lane & 15, quad = lane >> 4;
    const int pair = w >> 1, h = w & 1;
    const int q = h*16 + cl;                         // this wave's A-frag row (m = lane&15)
    const float b3v = b3[0];
    const float* w1c = W1 + 768*384;
    const float* w1d = W1 + 769*384;

    #pragma unroll 1
    for (int t4=0; t4<4; t4++){
        const int dcol = blockIdx.x*16 + t4*4 + pair;    // doc column, < 4096
        const float dsv = dense_in[q*4096 + dcol];
        const float ssv = sparse[q*4096 + dcol];

        f32x4 acc[12];
        #pragma unroll
        for (int t=0;t<12;t++) acc[t] = (f32x4){0.f,0.f,0.f,0.f};

        // prefetch s=0
        bf16x8 bw_c = *(const bf16x8*)(Bws + dcol*384 + quad*8);
        f32x4  a0_c = *(const f32x4*)(Aq + q*384 + quad*8);
        f32x4  a1_c = *(const f32x4*)(Aq + q*384 + quad*8 + 4);

        #pragma unroll 1
        for (int s=0;s<12;s++){
            const int k0 = s*32 + quad*8;
            const int kn = (s < 11) ? (k0 + 32) : (quad*8);  // dummy wrap on last iter
            const bf16x8 bw_n = *(const bf16x8*)(Bws + dcol*384 + kn);
            const f32x4  a0_n = *(const f32x4*)(Aq + q*384 + kn);
            const f32x4  a1_n = *(const f32x4*)(Aq + q*384 + kn + 4);
            const f32x4 wc0 = *(const f32x4*)(w1c + k0);
            const f32x4 wc1 = *(const f32x4*)(w1c + k0 + 4);
            const f32x4 wd0 = *(const f32x4*)(w1d + k0);
            const f32x4 wd1 = *(const f32x4*)(w1d + k0 + 4);
            bf16x8 fr;
            #pragma unroll
            for (int j=0;j<4;j++){
                float h0 = a0_c[j] + bf2f(bw_c[j])   + dsv*wc0[j] + ssv*wd0[j];
                float h1 = a1_c[j] + bf2f(bw_c[4+j]) + dsv*wc1[j] + ssv*wd1[j];
                fr[j]   = f2bf(fmaxf(h0, 0.0f));
                fr[4+j] = f2bf(fmaxf(h1, 0.0f));
            }
            #pragma unroll
            for (int t=0;t<12;t++){
                const bf16x8 bfr = *(const bf16x8*)(lw + ((s*12 + t)*64 + lane)*8);
                acc[t] = __builtin_amdgcn_mfma_f32_16x16x32_bf16(fr, bfr, acc[t], 0, 0, 0);
            }
            bw_c = bw_n; a0_c = a0_n; a1_c = a1_n;
        }

        // layer 3 over all 12 tiles (complete logit in-wave). D: col=lane&15 -> n, row=quad*4+r
        float p[4] = {0.f,0.f,0.f,0.f};
        #pragma unroll
        for (int t=0;t<12;t++){
            const float b2v = b2[t*16 + cl];
            const float w3v = W3[t*16 + cl];
            #pragma unroll
            for (int r=0;r<4;r++)
                p[r] += fmaxf(acc[t][r] + b2v, 0.0f) * w3v;
        }
        #pragma unroll
        for (int m=1; m<16; m<<=1){
            #pragma unroll
            for (int r=0;r<4;r++) p[r] += __shfl_xor(p[r], m);
        }
        if (cl == 0){
            #pragma unroll
            for (int r=0;r<4;r++){
                int qq = h*16 + quad*4 + r;
                float logit = p[r] + b3v;
                float wgt = 1.0f/(1.0f + __expf(-logit));
                float dd = dense_in[qq*4096 + dcol];
                float ss = sparse[qq*4096 + dcol];
                out_final[qq*4096 + dcol] = wgt*dd + (1.0f - wgt)*ss;
            }
        }
    }
}

// ---------------------------------------------------------------- launch
extern "C" void kernel_launch(void* const* d_in, const int* in_sizes, int n_in,
                              void* d_out, int out_size, void* d_ws, size_t ws_size,
                              hipStream_t stream){
    const float* query  = (const float*)d_in[0];
    const float* doc    = (const float*)d_in[1];
    const float* sparse = (const float*)d_in[2];
    const float* W1     = (const float*)d_in[3];
    const float* b1     = (const float*)d_in[4];
    const float* W2     = (const float*)d_in[5];
    const float* b2     = (const float*)d_in[6];
    const float* W3     = (const float*)d_in[7];
    const float* b3     = (const float*)d_in[8];

    float* out_final  = (float*)d_out;                 // [32,4096]
    float* out_dense  = (float*)d_out + 131072;        // [32,4096]
    float* out_sparse = (float*)d_out + 262144;        // [32,4096]

    // workspace layout (16B-aligned), total 3,194,880 B
    short* Bws = (short*)d_ws;                                    // 3,145,728 B  (bf16 [4096][384])
    float* Aq  = (float*)((char*)d_ws + 3145728);                 //    49,152 B  (f32  [32][384])

    hipLaunchKernelGGL(pre_kernel,  dim3(514), dim3(256), 0, stream,
                       query, doc, sparse, W1, b1, out_dense, out_sparse, Bws, Aq);
    hipLaunchKernelGGL(main_kernel, dim3(256), dim3(512), 0, stream,
                       Aq, Bws, W1, W2, b2, W3, b3, sparse, out_dense, out_final);
}

// Round 11
// 136.406 us; speedup vs baseline: 5.1747x; 1.0502x over previous
//
#include <hip/hip_runtime.h>
#include <hip/hip_bf16.h>

typedef __attribute__((ext_vector_type(4)))  float f32x4;
typedef __attribute__((ext_vector_type(16))) float f32x16;
typedef __attribute__((ext_vector_type(8)))  short bf16x8;

__device__ __forceinline__ short f2bf(float x){
    __hip_bfloat16 h = __float2bfloat16(x);
    return __builtin_bit_cast(short, h);
}
__device__ __forceinline__ float bf2f(short x){
    unsigned int u = ((unsigned int)(unsigned short)x) << 16;
    return __builtin_bit_cast(float, u);
}

// ---------------------------------------------------------------- pre: dense scores + sparse copy + AB GEMM + W1cd table
// blocks 0..255   : dense_sparse body (16 docs x 32 q each)
// blocks 256..511 : Bws(bf16)[16 doc rows] = doc @ W1b
// blocks 512..513 : Aq(f32)[16 q rows]     = query @ W1a + b1
// block  514      : W1cd bf16 table (768 shorts): o = (k>>3)*16 + which*8 + (k&7),
//                   which 0 = dense col of W1 (row 768), 1 = sparse col (row 769)
__global__ __launch_bounds__(256)
void pre_kernel(const float* __restrict__ query, const float* __restrict__ doc,
                const float* __restrict__ sparse, const float* __restrict__ W1,
                const float* __restrict__ b1,
                float* __restrict__ out_dense, float* __restrict__ out_sparse,
                short* __restrict__ Bws, float* __restrict__ Aq, short* __restrict__ W1cd){
    __shared__ float ldsq[32*388];
    __shared__ float ldsd[16*388];
    const int b = blockIdx.x, tid = threadIdx.x;

    if (b < 256){
        const int d0 = b*16;
        #pragma unroll
        for (int i=0;i<12;i++){ int idx = tid + i*256; int row = idx/96, c4 = idx%96;
            *(f32x4*)(ldsq + row*388 + c4*4) = *(const f32x4*)(query + row*384 + c4*4); }
        #pragma unroll
        for (int i=0;i<6;i++){ int idx = tid + i*256; int row = idx/96, c4 = idx%96;
            *(f32x4*)(ldsd + row*388 + c4*4) = *(const f32x4*)(doc + (d0+row)*384 + c4*4); }
        __syncthreads();
        const int q = tid>>3, dg = tid&7;
        float acc0 = 0.0f, acc1 = 0.0f;
        #pragma unroll 4
        for (int k=0;k<384;k++){
            float qv = ldsq[q*388 + k];
            acc0 += qv*ldsd[dg*388 + k];
            acc1 += qv*ldsd[(dg+8)*388 + k];
        }
        out_dense[q*4096 + d0 + dg]     = acc0;
        out_dense[q*4096 + d0 + dg + 8] = acc1;
        if (tid < 128){
            int qq = tid>>2, c4 = tid&3;
            *(f32x4*)(out_sparse + qq*4096 + d0 + c4*4) = *(const f32x4*)(sparse + qq*4096 + d0 + c4*4);
        }
    } else if (b < 514){
        const int bb = b - 256;
        const int w = tid >> 6, lane = tid & 63;
        const int cl = lane & 15, quad = lane >> 4;
        const float* src; const float* wrow; int r0; bool isA;
        if (bb < 256){ r0 = bb*16;       src = doc;   wrow = W1 + 384*384; isA = false; }
        else         { r0 = (bb-256)*16; src = query; wrow = W1;           isA = true;  }

        f32x4 acc[6];
        #pragma unroll
        for (int t=0;t<6;t++) acc[t] = (f32x4){0.f,0.f,0.f,0.f};

        #pragma unroll 1
        for (int s=0;s<12;s++){
            const float* ap = src + (r0+cl)*384 + s*32 + quad*8;
            const f32x4 a0 = *(const f32x4*)ap;
            const f32x4 a1 = *(const f32x4*)(ap+4);
            bf16x8 af;
            #pragma unroll
            for (int j=0;j<4;j++){ af[j] = f2bf(a0[j]); af[4+j] = f2bf(a1[j]); }
            const float* wk = wrow + (s*32 + quad*8)*384;
            #pragma unroll
            for (int tt=0;tt<6;tt++){
                const int col = (w*6+tt)*16 + cl;
                bf16x8 bf_;
                #pragma unroll
                for (int j=0;j<8;j++) bf_[j] = f2bf(wk[j*384 + col]);
                acc[tt] = __builtin_amdgcn_mfma_f32_16x16x32_bf16(af, bf_, acc[tt], 0, 0, 0);
            }
        }
        #pragma unroll
        for (int tt=0;tt<6;tt++){
            const int col = (w*6+tt)*16 + cl;
            if (isA){
                const float b1v = b1[col];
                #pragma unroll
                for (int r=0;r<4;r++)
                    Aq[(r0 + quad*4 + r)*384 + col] = acc[tt][r] + b1v;
            } else {
                #pragma unroll
                for (int r=0;r<4;r++)
                    Bws[(r0 + quad*4 + r)*384 + col] = f2bf(acc[tt][r]);
            }
        }
    } else {
        #pragma unroll
        for (int i=0;i<3;i++){
            int o3 = tid + i*256;                    // < 768
            int k = (o3>>4)*8 + (o3&7);              // < 384
            int which = (o3>>3)&1;
            W1cd[o3] = f2bf(W1[(768+which)*384 + k]);
        }
    }
}

// ---------------------------------------------------------------- main fused MLP kernel
// 256 blocks x 512 thr = 8 waves, 1 block/CU (LDS 147.5 KB). ONE wave owns one doc column x
// all 32 q rows x all 192 N via mfma_f32_32x32x16_bf16 (6 n-tiles of 32): each 1KB B-frag
// LDS read feeds 32x32x16 = 2x FLOP/LDS-byte vs round 10 -> per-CU LDS traffic halves.
// acc = 6 x f32x16 = 96 regs -> AGPRs (unified file; arch-VGPR working set stays ~70 < 128,
// the spill wall from rounds 5-7). fr built once chip-wide; zero barriers after staging.
// A-frag: m=lane&31, k=(lane>>5)*8+j.  B-frag: n=lane&31, same k.
// C/D: col=lane&31, row=(reg&3)+8*(reg>>2)+4*(lane>>5)  [m74/m101-verified].
__global__ __launch_bounds__(512, 2)
void main_kernel(const float* __restrict__ Aq, const short* __restrict__ Bws,
                 const short* __restrict__ W1cd,
                 const float* __restrict__ b2, const float* __restrict__ W3,
                 const float* __restrict__ b3, const float* __restrict__ sparse,
                 const float* __restrict__ W2, const float* __restrict__ dense_in,
                 float* __restrict__ out_final){
    __shared__ short lw[73728];                      // 147,456 B
    const int tid = threadIdx.x;
    // stage W2 -> LDS in 32x32-tile order: chunk c = (s*6+t2)*64+lane_c, reg j = W2[k][n],
    // n = t2*32+(lane_c&31), k = s*16+((lane_c>>5)&1)*8+j   (s<24 ksteps of 16, t2<6 n-tiles)
    #pragma unroll
    for (int i=0;i<18;i++){
        int c = tid + i*512;
        int lane_c = c & 63, st = c >> 6;            // st < 144
        int s = st/6, t2 = st%6;
        int n = t2*32 + (lane_c&31), kb = s*16 + ((lane_c>>5)&1)*8;
        bf16x8 v;
        #pragma unroll
        for (int j=0;j<8;j++) v[j] = f2bf(W2[(kb+j)*192 + n]);
        *(bf16x8*)(lw + c*8) = v;
    }
    __syncthreads();                                 // only barrier in the kernel

    const int lane = tid & 63, w = tid >> 6;
    const int m = lane & 31, q2 = lane >> 5;         // row m; k-half q2
    const int kbase = q2*8;
    const float b3v = b3[0];

    #pragma unroll 1
    for (int t4=0; t4<2; t4++){
        const int dcol = blockIdx.x*16 + t4*8 + w;   // doc column, < 4096
        const float dsv = dense_in[m*4096 + dcol];
        const float ssv = sparse[m*4096 + dcol];

        f32x16 acc[6];
        #pragma unroll
        for (int t=0;t<6;t++)
            #pragma unroll
            for (int r=0;r<16;r++) acc[t][r] = 0.0f;

        // prefetch s=0
        bf16x8 bw_c = *(const bf16x8*)(Bws + dcol*384 + kbase);
        f32x4  a0_c = *(const f32x4*)(Aq + m*384 + kbase);
        f32x4  a1_c = *(const f32x4*)(Aq + m*384 + kbase + 4);

        #pragma unroll 1
        for (int s=0;s<24;s++){
            const int k0 = s*16 + kbase;
            const int kn = (s < 23) ? (k0 + 16) : kbase;     // dummy wrap on last iter
            const bf16x8 bw_n = *(const bf16x8*)(Bws + dcol*384 + kn);
            const f32x4  a0_n = *(const f32x4*)(Aq + m*384 + kn);
            const f32x4  a1_n = *(const f32x4*)(Aq + m*384 + kn + 4);
            const bf16x8 wcv = *(const bf16x8*)(W1cd + (s*2 + q2)*16);
            const bf16x8 wdv = *(const bf16x8*)(W1cd + (s*2 + q2)*16 + 8);
            bf16x8 fr;
            #pragma unroll
            for (int j=0;j<4;j++){
                float h0 = a0_c[j] + bf2f(bw_c[j])   + dsv*bf2f(wcv[j])   + ssv*bf2f(wdv[j]);
                float h1 = a1_c[j] + bf2f(bw_c[4+j]) + dsv*bf2f(wcv[4+j]) + ssv*bf2f(wdv[4+j]);
                fr[j]   = f2bf(fmaxf(h0, 0.0f));
                fr[4+j] = f2bf(fmaxf(h1, 0.0f));
            }
            #pragma unroll
            for (int t=0;t<6;t++){
                const bf16x8 bfr = *(const bf16x8*)(lw + ((s*6 + t)*64 + lane)*8);
                acc[t] = __builtin_amdgcn_mfma_f32_32x32x16_bf16(fr, bfr, acc[t], 0, 0, 0);
            }
            bw_c = bw_n; a0_c = a0_n; a1_c = a1_n;
        }

        // layer 3: p[r] = sum_n relu(h2[row_r][n]+b2[n])*W3[n]; this lane covers n = t*32+m
        float p[16];
        #pragma unroll
        for (int r=0;r<16;r++) p[r] = 0.0f;
        #pragma unroll
        for (int t=0;t<6;t++){
            const int n = t*32 + m;
            const float b2v = b2[n];
            const float w3v = W3[n];
            #pragma unroll
            for (int r=0;r<16;r++)
                p[r] += fmaxf(acc[t][r] + b2v, 0.0f) * w3v;
        }
        // reduce over the 32 lanes of this q2 half (masks 1..16 stay within the half)
        #pragma unroll
        for (int mask=1; mask<32; mask<<=1){
            #pragma unroll
            for (int r=0;r<16;r++) p[r] += __shfl_xor(p[r], mask);
        }
        // lane m<16 takes p[m] (static cndmask chain; no dynamic reg indexing)
        float myp = p[0];
        #pragma unroll
        for (int r=1;r<16;r++) myp = (m==r) ? p[r] : myp;
        if (m < 16){
            const int row = (m&3) + 8*(m>>2) + 4*q2;
            float logit = myp + b3v;
            float wgt = 1.0f/(1.0f + __expf(-logit));
            float dd = dense_in[row*4096 + dcol];
            float ss = sparse[row*4096 + dcol];
            out_final[row*4096 + dcol] = wgt*dd + (1.0f - wgt)*ss;
        }
    }
}

// ---------------------------------------------------------------- launch
extern "C" void kernel_launch(void* const* d_in, const int* in_sizes, int n_in,
                              void* d_out, int out_size, void* d_ws, size_t ws_size,
                              hipStream_t stream){
    const float* query  = (const float*)d_in[0];
    const float* doc    = (const float*)d_in[1];
    const float* sparse = (const float*)d_in[2];
    const float* W1     = (const float*)d_in[3];
    const float* b1     = (const float*)d_in[4];
    const float* W2     = (const float*)d_in[5];
    const float* b2     = (const float*)d_in[6];
    const float* W3     = (const float*)d_in[7];
    const float* b3     = (const float*)d_in[8];

    float* out_final  = (float*)d_out;                 // [32,4096]
    float* out_dense  = (float*)d_out + 131072;        // [32,4096]
    float* out_sparse = (float*)d_out + 262144;        // [32,4096]

    // workspace layout (16B-aligned), total 3,196,416 B
    short* Bws  = (short*)d_ws;                                   // 3,145,728 B  (bf16 [4096][384])
    float* Aq   = (float*)((char*)d_ws + 3145728);                //    49,152 B  (f32  [32][384])
    short* W1cd = (short*)((char*)d_ws + 3194880);                //     1,536 B

    hipLaunchKernelGGL(pre_kernel,  dim3(515), dim3(256), 0, stream,
                       query, doc, sparse, W1, b1, out_dense, out_sparse, Bws, Aq, W1cd);
    hipLaunchKernelGGL(main_kernel, dim3(256), dim3(512), 0, stream,
                       Aq, Bws, W1cd, b2, W3, b3, sparse, W2, out_dense, out_final);
}